// Round 10
// baseline (48.680 us; speedup 1.0000x reference)
//
#include <hip/hip_runtime.h>

#define NA 3
#define NT 32
#define NC 4
#define NR 8
#define NK 1024
#define NPIX 4096            // 64*64
#define NOUT (NT * NC * NK)  // 131072 complex outputs
#define TILE 1024            // pixels per LDS tile (49152 B)
#define NTILE 4
#define KP 4                 // k-values per thread

// ---------------------------------------------------------------------------
// detect_kernel: disambiguate the two 16384-float inputs (trj vs mps).
// trj strictly in (-pi,pi); mps ~ N(0,1) has ~27 samples |v|>3.1416.
// flag=1 => candA is mps.  [proven r7-r9]
// ---------------------------------------------------------------------------
__global__ __launch_bounds__(1024) void detect_kernel(const float* __restrict__ A,
                                                      const float* __restrict__ B,
                                                      int* __restrict__ flag) {
    __shared__ int bigA, bigB;
    if (threadIdx.x == 0) { bigA = 0; bigB = 0; }
    __syncthreads();
    int a = 0, b = 0;
    for (int i = threadIdx.x; i < 16384; i += 1024) {
        if (fabsf(A[i]) > 3.1416f) a = 1;
        if (fabsf(B[i]) > 3.1416f) b = 1;
    }
    if (a) atomicOr(&bigA, 1);
    if (b) atomicOr(&bigB, 1);
    __syncthreads();
    if (threadIdx.x == 0) flag[0] = (bigA && !bigB) ? 1 : 0;
}

// ---------------------------------------------------------------------------
// nudft4_kernel: y[a,r,c,k] = sum_n s[a,c,n]*exp(-i*(t0*(i-32)+t1*(j-32)))
// Block: 256 thr = 4 waves (kk) x 64 ch; thread owns KP=4 k's
// (k0 = bx*16 + kk*4), column j=ch, walks rows i=0..63 (pixel stride 64).
// Row step: phase += t0 -> one rotation exp(-i*t0) per k (4 FMA, no sincos).
// s = x*mps staged in LDS 1024 px/tile; one float4 LDS read feeds 32 FMA.
// ---------------------------------------------------------------------------
#define ACC4V(V, B, j, cR, cI)                                        \
    accr[j][B + 0] = fmaf(V.x, cR, accr[j][B + 0]);                   \
    acci[j][B + 0] = fmaf(V.x, cI, acci[j][B + 0]);                   \
    accr[j][B + 1] = fmaf(V.y, cR, accr[j][B + 1]);                   \
    acci[j][B + 1] = fmaf(V.y, cI, acci[j][B + 1]);                   \
    accr[j][B + 2] = fmaf(V.z, cR, accr[j][B + 2]);                   \
    acci[j][B + 2] = fmaf(V.z, cI, acci[j][B + 2]);                   \
    accr[j][B + 3] = fmaf(V.w, cR, accr[j][B + 3]);                   \
    acci[j][B + 3] = fmaf(V.w, cI, acci[j][B + 3]);

__global__ __launch_bounds__(256, 3) void nudft4_kernel(
    const float* __restrict__ x,
    const float* __restrict__ candA,
    const float* __restrict__ candB,
    const int*  __restrict__ flag,
    float2* __restrict__ y)
{
    __shared__ float4 tile[TILE * 3];   // [pixel][12 floats]

    const int fl = flag[0];
    const float* __restrict__ trj = fl ? candB : candA;
    const float* __restrict__ mps = fl ? candA : candB;

    const int tid = threadIdx.x;
    const int kk  = tid >> 6;    // wave 0..3
    const int ch  = tid & 63;    // column j
    const int k0  = blockIdx.x * 16 + kk * KP;
    const int r   = blockIdx.y;

    float curR[KP], curI[KP], rotR[KP], rotI[KP];
    float accr[KP][12], acci[KP][12];
#pragma unroll
    for (int j = 0; j < KP; ++j) {
        const float t0 = trj[(r * 2 + 0) * NK + k0 + j];
        const float t1 = trj[(r * 2 + 1) * NK + k0 + j];
        float sr, cr; sincosf(t0, &sr, &cr);       // rot = exp(-i*t0)
        rotR[j] = cr; rotI[j] = sr;
        float s0, c0; sincosf(-32.f * t0 + (float)(ch - 32) * t1, &s0, &c0);
        curR[j] = c0; curI[j] = -s0;               // cur = exp(-i*ph0)
#pragma unroll
        for (int c = 0; c < 12; ++c) { accr[j][c] = 0.f; acci[j][c] = 0.f; }
    }

    for (int h = 0; h < NTILE; ++h) {
        if (h) __syncthreads();          // previous tile fully consumed
        // stage tile h: fold s = x*mps on the fly (4 pixels/thread)
#pragma unroll
        for (int mm = 0; mm < TILE / 256; ++mm) {
            const int m = tid + mm * 256;
            const int n = h * TILE + m;
            const float x0 = x[n], x1 = x[NPIX + n], x2 = x[2 * NPIX + n];
            const float m0 = mps[n], m1 = mps[NPIX + n],
                        m2 = mps[2 * NPIX + n], m3 = mps[3 * NPIX + n];
            tile[m * 3 + 0] = make_float4(x0 * m0, x0 * m1, x0 * m2, x0 * m3);
            tile[m * 3 + 1] = make_float4(x1 * m0, x1 * m1, x1 * m2, x1 * m3);
            tile[m * 3 + 2] = make_float4(x2 * m0, x2 * m1, x2 * m2, x2 * m3);
        }
        __syncthreads();

        const float4* tp = tile + ch * 3;
        float4 e0 = tp[0], e1 = tp[1], e2 = tp[2];
        for (int q = 0; q < 16; ++q) {   // rows h*16+q, pixel m = ch + 64q
            const float4* nx = tp + ((q + 1) & 15) * 192;   // prefetch next row
            float4 f0 = nx[0], f1 = nx[1], f2 = nx[2];

#pragma unroll
            for (int j = 0; j < KP; ++j) {
                const float cR = curR[j], cI = curI[j];
                ACC4V(e0, 0, j, cR, cI)
                ACC4V(e1, 4, j, cR, cI)
                ACC4V(e2, 8, j, cR, cI)
                const float nr = fmaf(cR, rotR[j],  cI * rotI[j]);
                const float ni = fmaf(cI, rotR[j], -cR * rotI[j]);
                curR[j] = nr; curI[j] = ni;
            }
            e0 = f0; e1 = f1; e2 = f2;
        }
    }

    // full-wave reduction over the 64 columns, then lane 0 writes
#pragma unroll
    for (int j = 0; j < KP; ++j) {
#pragma unroll
        for (int c = 0; c < 12; ++c) {
            float vr = accr[j][c], vi = acci[j][c];
#pragma unroll
            for (int m = 32; m >= 1; m >>= 1) {
                vr += __shfl_xor(vr, m); vi += __shfl_xor(vi, m);
            }
            if (ch == 0) {
                const int a = c >> 2, cc = c & 3;
                y[((a * NR + r) * NC + cc) * NK + k0 + j] = make_float2(vr, vi);
            }
        }
    }
}

// ---------------------------------------------------------------------------
// combine_kernel: out planar f32 (re @ [gid], im @ [NOUT+gid]),
// gid = t*4096 + c*1024 + k.   [layout proven r7-r9]
// out[t,c,k] = dcf[r,k] * sum_a phi[a,t] * y[a,r,c,k],  r = sidx[t]
// ---------------------------------------------------------------------------
__global__ __launch_bounds__(256) void combine_kernel(const float* __restrict__ phi,
                                                      const float* __restrict__ dcf,
                                                      const int* __restrict__ sidx,
                                                      const float2* __restrict__ y,
                                                      float* __restrict__ out) {
    int gid = blockIdx.x * 256 + threadIdx.x;
    int k = gid & (NK - 1);
    int c = (gid >> 10) & (NC - 1);
    int t = gid >> 12;

    // in-bounds int64-vs-int32 detection (words 0..31; P(false+)=8^-16)
    bool is64 = true;
#pragma unroll
    for (int i = 1; i < 32; i += 2) is64 = is64 && (sidx[i] == 0);
    int r = is64 ? sidx[2 * t] : sidx[t];

    float d = dcf[r * NK + k];
    float ore = 0.f, oim = 0.f;
#pragma unroll
    for (int a = 0; a < NA; ++a) {
        float p = phi[a * NT + t];
        float2 v = y[((a * NR + r) * NC + c) * NK + k];
        ore = fmaf(p, v.x, ore);
        oim = fmaf(p, v.y, oim);
    }
    out[gid]        = ore * d;
    out[NOUT + gid] = oim * d;
}

// ---------------------------------------------------------------------------
extern "C" void kernel_launch(void* const* d_in, const int* in_sizes, int n_in,
                              void* d_out, int out_size, void* d_ws, size_t ws_size,
                              hipStream_t stream) {
    // size-signature input resolution (robust to permutation; doc order default)
    int ix = 0, i16a = 1, iphi = 2, i16b = 3, idcf = 4, isidx = 5;
    int f16[2]; int n16 = 0, fx = -1, fphi = -1, fdcf = -1, fsidx = -1;
    for (int i = 0; i < n_in; ++i) {
        const int s = in_sizes[i];
        if (s == 12288) fx = i;
        else if (s == 96) fphi = i;
        else if (s == 8192) fdcf = i;
        else if (s == 16384) { if (n16 < 2) f16[n16] = i; ++n16; }
        else if (s == 32 || s == 64) fsidx = i;
    }
    if (fx >= 0 && fphi >= 0 && fdcf >= 0 && fsidx >= 0 && n16 == 2) {
        ix = fx; iphi = fphi; idcf = fdcf; isidx = fsidx;
        i16a = f16[0]; i16b = f16[1];
    }

    const float* x    = (const float*)d_in[ix];
    const float* cA   = (const float*)d_in[i16a];
    const float* cB   = (const float*)d_in[i16b];
    const float* phi  = (const float*)d_in[iphi];
    const float* dcf  = (const float*)d_in[idcf];
    const int*   sidx = (const int*)d_in[isidx];

    // workspace: flag @0 | y (A*R*C*K float2 = 786432 B) @256
    int*    flag = (int*)d_ws;
    float2* y    = (float2*)((char*)d_ws + 256);

    detect_kernel<<<1, 1024, 0, stream>>>(cA, cB, flag);
    nudft4_kernel<<<dim3(NK / 16, NR), 256, 0, stream>>>(x, cA, cB, flag, y);
    combine_kernel<<<NOUT / 256, 256, 0, stream>>>(phi, dcf, sidx, y, (float*)d_out);
}

// Round 11
// 23.105 us; speedup vs baseline: 2.1069x; 2.1069x over previous
//
#include <hip/hip_runtime.h>
#include <hip/hip_bf16.h>

#define NA 3
#define NT 32
#define NC 4
#define NR 8
#define NK 1024
#define NPIX 4096            // 64*64
#define NOUT (NT * NC * NK)  // 131072 complex outputs
#define NRK (NR * NK)        // 8192 (r,k) pairs

typedef __attribute__((ext_vector_type(8))) short bf16x8;
typedef __attribute__((ext_vector_type(4))) float f32x4;

static __device__ __forceinline__ short f2bf(float f) {
    union { __hip_bfloat16 h; short s; } u;
    u.h = __float2bfloat16(f);
    return u.s;
}

// ---------------------------------------------------------------------------
// detect_kernel: trj strictly in (-pi,pi); mps ~ N(0,1) has ~27 |v|>3.1416.
// flag=1 => candA is mps.  [proven r7-r10]
// ---------------------------------------------------------------------------
__global__ __launch_bounds__(1024) void detect_kernel(const float* __restrict__ A,
                                                      const float* __restrict__ B,
                                                      int* __restrict__ flag) {
    __shared__ int bigA, bigB;
    if (threadIdx.x == 0) { bigA = 0; bigB = 0; }
    __syncthreads();
    int a = 0, b = 0;
    for (int i = threadIdx.x; i < 16384; i += 1024) {
        if (fabsf(A[i]) > 3.1416f) a = 1;
        if (fabsf(B[i]) > 3.1416f) b = 1;
    }
    if (a) atomicOr(&bigA, 1);
    if (b) atomicOr(&bigB, 1);
    __syncthreads();
    if (threadIdx.x == 0) flag[0] = (bigA && !bigB) ? 1 : 0;
}

// ---------------------------------------------------------------------------
// nudft_mfma_kernel: y[ch, rk] = sum_n s[ch,n] * E[n,rk] via 16x16x32 bf16 MFMA.
//   E[n,rk] = exp(-i*(t0*(i-32)+t1*(j-32))), n = i*64+j, generated in-register
//   by rotation recurrence (tile of 32 px = half row; even tile: *exp(-i*32*t1),
//   odd tile: *exp(-i*(t0-32*t1))).
// Block: 256 thr = 4 waves; wave owns 16 rk columns (col = lane&15), lane
// holds pixel slots off = (lane>>4)*8 + e, e=0..7 -- SAME slot rule for A and
// B fragments, so correctness is invariant to the HW k-permutation.
// s staged in LDS as bf16 [16ch][2048px], swizzled byte ^= ((ch&7)<<4).
// n-split S across blocks: block bx -> (chunk = bx&127, p = bx>>7); partial
// y stored per split, reduced in combine.
// ---------------------------------------------------------------------------
__global__ __launch_bounds__(256, 2) void nudft_mfma_kernel(
    const float* __restrict__ x,
    const float* __restrict__ candA,
    const float* __restrict__ candB,
    const int*  __restrict__ flag,
    float2* __restrict__ y2,     // [S*12][NRK]
    int S)
{
    __shared__ short slds[16 * 2048];   // 64 KiB

    const int fl = flag[0];
    const float* __restrict__ trj = fl ? candB : candA;
    const float* __restrict__ mps = fl ? candA : candB;

    const int tid   = threadIdx.x;
    const int chunk = blockIdx.x & 127;
    const int p     = blockIdx.x >> 7;        // n-split index (0..S-1)
    const int w     = tid >> 6;               // wave 0..3
    const int l     = tid & 63;
    const int col   = l & 15;                 // rk column within wave's 16
    const int g     = l >> 4;                 // k-slot group 0..3

    const int rk = chunk * 64 + w * 16 + col;
    const int r  = rk >> 10;
    const int k  = rk & (NK - 1);

    const float t0 = trj[(r * 2 + 0) * NK + k];
    const float t1 = trj[(r * 2 + 1) * NK + k];

    // tile-step rotations: even tile -> exp(-i*32*t1); odd -> exp(-i*(t0-32*t1))
    float sA, cA; sincosf(32.f * t1, &sA, &cA);
    float sB, cB; sincosf(t0 - 32.f * t1, &sB, &cB);

    // cur[e] = exp(-i*phase) at pixel n = n0 + g*8 + e  (i = n0/64, j = g*8+e)
    const int n0 = p * (NPIX / S);
    const float fi0 = (float)((n0 >> 6) - 32);
    float curR[8], curI[8];
#pragma unroll
    for (int e = 0; e < 8; ++e) {
        float ph = fmaf(t1, (float)(g * 8 + e - 32), t0 * fi0);
        float s_, c_; sincosf(ph, &s_, &c_);
        curR[e] = c_; curI[e] = -s_;
    }

    f32x4 accRe = {0.f, 0.f, 0.f, 0.f};
    f32x4 accIm = {0.f, 0.f, 0.f, 0.f};

    const int nchunks = (S == 1) ? 2 : 1;     // LDS holds 2048 px per pass
    for (int hc = 0; hc < nchunks; ++hc) {
        if (hc) __syncthreads();
        // ---- stage 2048 px: thread handles 8 consecutive pixels ----
        {
            const int m0 = tid * 8;                 // local pixel base
            const int nn = n0 + hc * 2048 + m0;     // global pixel
            float4 xv[3][2], mv[4][2];
#pragma unroll
            for (int a = 0; a < 3; ++a) {
                xv[a][0] = *(const float4*)&x[a * NPIX + nn];
                xv[a][1] = *(const float4*)&x[a * NPIX + nn + 4];
            }
#pragma unroll
            for (int c = 0; c < 4; ++c) {
                mv[c][0] = *(const float4*)&mps[c * NPIX + nn];
                mv[c][1] = *(const float4*)&mps[c * NPIX + nn + 4];
            }
#pragma unroll
            for (int a = 0; a < 3; ++a) {
#pragma unroll
                for (int c = 0; c < 4; ++c) {
                    const int chn = a * 4 + c;
                    union { bf16x8 v; short s[8]; } pk;
#pragma unroll
                    for (int e = 0; e < 8; ++e) {
                        const float xe = ((const float*)&xv[a][e >> 2])[e & 3];
                        const float me = ((const float*)&mv[c][e >> 2])[e & 3];
                        pk.s[e] = f2bf(xe * me);
                    }
                    const int byteoff = (chn * 4096 + m0 * 2) ^ ((chn & 7) << 4);
                    *(bf16x8*)((char*)slds + byteoff) = pk.v;
                }
            }
        }
        __syncthreads();

        // ---- 64 tiles of 32 px (unroll 2 so rotation parity is static) ----
        for (int lt = 0; lt < 64; lt += 2) {
#pragma unroll
            for (int par = 0; par < 2; ++par) {
                const int nloc = (lt + par) * 32 + g * 8;
                const int abyte = (col * 4096 + nloc * 2) ^ ((col & 7) << 4);
                const bf16x8 afrag = *(const bf16x8*)((const char*)slds + abyte);

                union { bf16x8 v; short s[8]; } bre, bim;
#pragma unroll
                for (int e = 0; e < 8; ++e) {
                    bre.s[e] = f2bf(curR[e]);
                    bim.s[e] = f2bf(curI[e]);
                }
                accRe = __builtin_amdgcn_mfma_f32_16x16x32_bf16(afrag, bre.v, accRe, 0, 0, 0);
                accIm = __builtin_amdgcn_mfma_f32_16x16x32_bf16(afrag, bim.v, accIm, 0, 0, 0);

                const float cd = par ? cB : cA;
                const float sd = par ? sB : sA;
#pragma unroll
                for (int e = 0; e < 8; ++e) {
                    const float nr = fmaf(curR[e], cd, curI[e] * sd);
                    const float ni = fmaf(curI[e], cd, -curR[e] * sd);
                    curR[e] = nr; curI[e] = ni;
                }
            }
        }
    }

    // ---- store C: row = g*4 + reg (channels 0..11; g==3 rows are pad) ----
    if (g < 3) {
#pragma unroll
        for (int reg = 0; reg < 4; ++reg) {
            const int chn = g * 4 + reg;
            y2[(p * 12 + chn) * NRK + rk] = make_float2(accRe[reg], accIm[reg]);
        }
    }
}

// ---------------------------------------------------------------------------
// combine_kernel: out planar f32 (re @ [gid], im @ [NOUT+gid]),
// gid = t*4096 + c*1024 + k.  [layout proven r7-r10]
// out[t,c,k] = dcf[r,k] * sum_a phi[a,t] * sum_p y2[p*12 + a*4+c][r*1024+k]
// ---------------------------------------------------------------------------
__global__ __launch_bounds__(256) void combine_kernel(const float* __restrict__ phi,
                                                      const float* __restrict__ dcf,
                                                      const int* __restrict__ sidx,
                                                      const float2* __restrict__ y2,
                                                      float* __restrict__ out,
                                                      int S) {
    int gid = blockIdx.x * 256 + threadIdx.x;
    int k = gid & (NK - 1);
    int c = (gid >> 10) & (NC - 1);
    int t = gid >> 12;

    // in-bounds int64-vs-int32 detection (words 0..31; P(false+)=8^-16)
    bool is64 = true;
#pragma unroll
    for (int i = 1; i < 32; i += 2) is64 = is64 && (sidx[i] == 0);
    int r = is64 ? sidx[2 * t] : sidx[t];

    float d = dcf[r * NK + k];
    float ore = 0.f, oim = 0.f;
#pragma unroll
    for (int a = 0; a < NA; ++a) {
        float pphi = phi[a * NT + t];
        for (int p = 0; p < S; ++p) {
            float2 v = y2[(p * 12 + a * 4 + c) * NRK + r * NK + k];
            ore = fmaf(pphi, v.x, ore);
            oim = fmaf(pphi, v.y, oim);
        }
    }
    out[gid]        = ore * d;
    out[NOUT + gid] = oim * d;
}

// ---------------------------------------------------------------------------
extern "C" void kernel_launch(void* const* d_in, const int* in_sizes, int n_in,
                              void* d_out, int out_size, void* d_ws, size_t ws_size,
                              hipStream_t stream) {
    // size-signature input resolution (robust to permutation; doc order default)
    int ix = 0, i16a = 1, iphi = 2, i16b = 3, idcf = 4, isidx = 5;
    int f16[2]; int n16 = 0, fx = -1, fphi = -1, fdcf = -1, fsidx = -1;
    for (int i = 0; i < n_in; ++i) {
        const int s = in_sizes[i];
        if (s == 12288) fx = i;
        else if (s == 96) fphi = i;
        else if (s == 8192) fdcf = i;
        else if (s == 16384) { if (n16 < 2) f16[n16] = i; ++n16; }
        else if (s == 32 || s == 64) fsidx = i;
    }
    if (fx >= 0 && fphi >= 0 && fdcf >= 0 && fsidx >= 0 && n16 == 2) {
        ix = fx; iphi = fphi; idcf = fdcf; isidx = fsidx;
        i16a = f16[0]; i16b = f16[1];
    }

    const float* x    = (const float*)d_in[ix];
    const float* cA   = (const float*)d_in[i16a];
    const float* cB   = (const float*)d_in[i16b];
    const float* phi  = (const float*)d_in[iphi];
    const float* dcf  = (const float*)d_in[idcf];
    const int*   sidx = (const int*)d_in[isidx];

    // n-split: S=2 if workspace fits both partials, else proven-size S=1
    const size_t need2 = 256 + (size_t)2 * 12 * NRK * sizeof(float2);
    const int S = (ws_size >= need2) ? 2 : 1;

    int*    flag = (int*)d_ws;
    float2* y2   = (float2*)((char*)d_ws + 256);

    detect_kernel<<<1, 1024, 0, stream>>>(cA, cB, flag);
    nudft_mfma_kernel<<<128 * S, 256, 0, stream>>>(x, cA, cB, flag, y2, S);
    combine_kernel<<<NOUT / 256, 256, 0, stream>>>(phi, dcf, sidx, y2,
                                                   (float*)d_out, S);
}